// Round 11
// baseline (310.110 us; speedup 1.0000x reference)
//
#include <hip/hip_runtime.h>
#include <hip/hip_bf16.h>

typedef __hip_bfloat16 bf16;
using short8  = __attribute__((ext_vector_type(8))) short;
using floatx4 = __attribute__((ext_vector_type(4))) float;

__device__ __forceinline__ float b2f(unsigned short u) {
    union { unsigned int i; float f; } v; v.i = ((unsigned int)u) << 16; return v.f;
}
__device__ __forceinline__ unsigned short f2b(float f) {
    bf16 h = __float2bfloat16(f);
    return *(unsigned short*)&h;
}

// ---------------------------------------------------------------------------
// Workspace layout (bytes) -- NON-OVERLAPPING:
//   dynk  @ 0         : fp32 (k1 6144 | k2T 131072 | k3T 147456 | k4T 524288 | k5T 262144 els)
//   stats @ 4284416   : 30720 fp32, 16 replicas per layer -> ends 4407296
//   WT    @ 4407296   : bf16 -> ends 5275648
//   S1    @ 5308416   : bf16, 33554432 elems. y1 during L1/L2; then A3/y3/A4/y4/A5.
//   S2    @ 72417280  : bf16, y2 = 16777216 elems (33.5 MB)
//
// MEASURED THIS SESSION:
//   r4: gemm_dw L3-L5 fusion REGRESSION -> reverted. gemm2 128row=68.4us.
//   r5: 64-row split REGRESSION (100.1us; VGPR cliff at 128 identified).
//   r6: launch_bounds(256,4) not honored w/ full-unroll staging (VGPR 136);
//       LDS 41472 also capped at 3/CU. total 320.8.
//   r8 (=r7 queued): SK=68 (LDS 39424) + unroll-1 batch-4 staging ->
//       VGPR 64, occ 28%, bank-conflict 1.34M->131K, gemm2 55.9us,
//       TOTAL 308.5us (best). Remaining: stall-dominated (HBM 17%,
//       VALU 27%, Mfma 1.4%) -- 16 serial load-stops/thread.
//   r9/r10 (queued, broker down x2): batch-4 -> batch-8 (8 stops, v[8]=32
//       regs in flight; predict VGPR 76-96 <= 128, dur 46-50; abort >128).
// HARD-WON RULES (session 1): disjoint ws regions WITH sizes; no threadfence
//   in wide epilogues; fusion only where it doesn't duplicate work.
// ---------------------------------------------------------------------------
#define NREP 16

// Merged head kernel: blocks 0..4185 = dyn-kernel prep (block 4185 also does
// housekeeping); blocks 4186..4609 = weight transpose-convert.
__global__ __launch_bounds__(256) void prep_wt_kernel(
    const int* __restrict__ label, const float* __restrict__ emb,
    const float* __restrict__ l1w, const float* __restrict__ l1b,
    const float* __restrict__ l2w, const float* __restrict__ l2b,
    const float* __restrict__ l3w, const float* __restrict__ l3b,
    const float* __restrict__ l4w, const float* __restrict__ l4b,
    const float* __restrict__ l5w, const float* __restrict__ l5b,
    float* __restrict__ dynk, float* __restrict__ stats,
    float* __restrict__ labelOut,
    const float* __restrict__ w2, const float* __restrict__ w3,
    const float* __restrict__ w4, const float* __restrict__ w5,
    bf16* __restrict__ wt2, bf16* __restrict__ wt3,
    bf16* __restrict__ wt4, bf16* __restrict__ wt5)
{
    __shared__ float T[32][33];
    const int tid = threadIdx.x;

    if (blockIdx.x >= 4186) {                            // ---- wt path ----
        int t = blockIdx.x - 4186;
        const float* W; bf16* WT; int K, N, tl;
        if (t < 8)        { W = w2; WT = wt2; K = 64;  N = 128; tl = t; }
        else if (t < 40)  { W = w3; WT = wt3; K = 128; N = 256; tl = t - 8; }
        else if (t < 168) { W = w4; WT = wt4; K = 256; N = 512; tl = t - 40; }
        else              { W = w5; WT = wt5; K = 512; N = 512; tl = t - 168; }
        const int NT = N >> 5;
        const int kt = tl / NT, nt = tl - kt * NT;
        const int k0 = kt * 32, n0 = nt * 32;
        const int cc = tid & 31, rr = tid >> 5;
        #pragma unroll
        for (int it = 0; it < 4; ++it) {
            int k = rr + it * 8;
            T[k][cc] = W[(long)(k0 + k) * N + n0 + cc];
        }
        __syncthreads();
        #pragma unroll
        for (int it = 0; it < 4; ++it) {
            int n = rr + it * 8;
            WT[(long)(n0 + n) * K + k0 + cc] = __float2bfloat16(T[cc][n]);
        }
        return;
    }

    if (blockIdx.x == 4185) {                            // housekeeping block
        for (int i = tid; i < 30720; i += 256) stats[i] = 0.0f;
        if (tid < 128) labelOut[tid] = (float)label[tid];
        return;
    }

    int idx = blockIdx.x * 256 + tid;                    // ---- prep path ----
    if (idx >= 1071104) return;
    const float* w; const float* bb; int loc, ckk, ksk, base;
    if (idx < 6144)        { w = l1w; bb = l1b; loc = idx;          ckk = 48;   ksk = 0;  base = 0;      }
    else if (idx < 137216) { w = l2w; bb = l2b; loc = idx - 6144;   ckk = 1024; ksk = 16; base = 6144;   }
    else if (idx < 284672) { w = l3w; bb = l3b; loc = idx - 137216; ckk = 1152; ksk = 9;  base = 137216; }
    else if (idx < 808960) { w = l4w; bb = l4b; loc = idx - 284672; ckk = 4096; ksk = 16; base = 284672; }
    else                   { w = l5w; bb = l5b; loc = idx - 808960; ckk = 2048; ksk = 4;  base = 808960; }
    int b   = loc / ckk;
    int col = loc - b * ckk;
    int lab = label[b];
    float acc = bb[col];
    #pragma unroll
    for (int m = 0; m < 5; ++m)
        acc = fmaf(emb[lab * 5 + m], w[m * ckk + col], acc);
    float val = tanhf(acc);
    if (ksk == 0) {
        dynk[idx] = val;                          // layer 1: [b][c*k*k]
    } else {
        int c  = col / ksk;                       // transposed: [b][tap][c]
        int t  = col - c * ksk;
        int Cl = ckk / ksk;
        dynk[base + b * ckk + t * Cl + c] = val;
    }
}

// ---------------------------------------------------------------------------
// Layer 1 v6: 32w x 8h tile per block, 256 threads, 2048 blocks, ~20 KB LDS.
// ---------------------------------------------------------------------------
__global__ __launch_bounds__(256) void fused_l1_v6(
    const float* __restrict__ xf, const float* __restrict__ dynk,
    const float* __restrict__ W, const float* __restrict__ bias,
    bf16* __restrict__ y, float* __restrict__ statsOut)
{
    constexpr int HIN = 128, HOUT = 64;
    constexpr int TW = 32, TH = 8;
    constexpr int PS  = 68;
    constexpr int PCH = 18 * PS;

    __shared__ float patch[3 * PCH];
    __shared__ __align__(16) float dwT[32 * 28];
    __shared__ float Wlds[192];
    __shared__ float klds[48];
    __shared__ float biasL[64];
    __shared__ float sums[64], sqs[64];

    const int tid = threadIdx.x;
    const int b   = blockIdx.x >> 4;
    const int tl  = blockIdx.x & 15;
    const int ty0 = (tl >> 1) * TH;
    const int tx0 = (tl & 1) * TW;

    if (tid < 48) klds[tid] = dynk[b * 48 + tid];
    if (tid >= 64 && tid < 256) Wlds[tid - 64] = W[tid - 64];
    if (tid < 64) { biasL[tid] = bias[tid]; sums[tid] = 0.f; sqs[tid] = 0.f; }

    {
        const int iy0 = ty0 * 2 - 1, ix0 = tx0 * 2 - 1;
        #pragma unroll
        for (int k = 0; k < 15; ++k) {
            int i  = tid + k * 256;
            int c  = i / 1224;
            int r  = i - c * 1224;
            int py = r / 68, px = r - py * 68;
            int gy = iy0 + py, gx = ix0 + px;
            bool slot = (i < 3672);
            bool inb  = slot && (px < 66) &&
                        ((unsigned)gy < (unsigned)HIN) && ((unsigned)gx < (unsigned)HIN);
            float v = 0.f;
            if (inb) v = xf[((long)b * 3 + c) * (HIN * HIN) + gy * HIN + gx];
            if (slot) patch[c * PCH + py * PS + px] = v;
        }
    }
    __syncthreads();

    {
        const int py = tid >> 5, px = tid & 31;
        const int pixg = tid >> 3, j = tid & 7;
        #pragma unroll
        for (int c = 0; c < 3; ++c) {
            const float* pb = &patch[c * PCH + (py * 2) * PS + px * 2];
            float a = 0.f;
            #pragma unroll
            for (int kh = 0; kh < 4; ++kh)
                #pragma unroll
                for (int kw = 0; kw < 4; ++kw)
                    a = fmaf(pb[kh * PS + kw], klds[c * 16 + kh * 4 + kw], a);
            dwT[pixg * 28 + j * 3 + c] = a;
        }
    }
    __syncthreads();

    {
        const int cq = tid & 7, pixg = tid >> 3;
        const int d0 = cq * 8;
        float Wr[3][8], bi[8];
        #pragma unroll
        for (int c = 0; c < 3; ++c)
            #pragma unroll
            for (int t = 0; t < 8; ++t) Wr[c][t] = Wlds[c * 64 + d0 + t];
        #pragma unroll
        for (int t = 0; t < 8; ++t) bi[t] = biasL[d0 + t];

        float dv[24];
        #pragma unroll
        for (int q4 = 0; q4 < 6; ++q4)
            *(float4*)&dv[q4 * 4] = *(const float4*)&dwT[pixg * 28 + q4 * 4];

        float sreg[8] = {}, qreg[8] = {};
        #pragma unroll
        for (int j = 0; j < 8; ++j) {
            const int pos = pixg * 8 + j;
            const float dv0 = dv[j * 3 + 0];
            const float dv1 = dv[j * 3 + 1];
            const float dv2 = dv[j * 3 + 2];
            const int py = pos >> 5, px = pos & 31;
            const long row = ((long)(b * HOUT + ty0 + py)) * HOUT + tx0 + px;
            union { uint4 v; unsigned short us[8]; } pk;
            #pragma unroll
            for (int t = 0; t < 8; ++t) {
                float v = fmaf(dv0, Wr[0][t], fmaf(dv1, Wr[1][t], fmaf(dv2, Wr[2][t], bi[t])));
                v = v > 0.f ? v : 0.2f * v;
                sreg[t] += v;
                qreg[t] = fmaf(v, v, qreg[t]);
                pk.us[t] = f2b(v);
            }
            *(uint4*)&y[row * 64 + d0] = pk.v;
        }
        #pragma unroll
        for (int m = 8; m < 64; m <<= 1)
            #pragma unroll
            for (int t = 0; t < 8; ++t) {
                sreg[t] += __shfl_xor(sreg[t], m);
                qreg[t] += __shfl_xor(qreg[t], m);
            }
        if ((tid & 63) < 8) {
            #pragma unroll
            for (int t = 0; t < 8; ++t) {
                atomicAdd(&sums[d0 + t], sreg[t]);
                atomicAdd(&sqs [d0 + t], qreg[t]);
            }
        }
    }
    __syncthreads();
    {
        const int rep = blockIdx.x & (NREP - 1);
        if (tid < 64) {
            atomicAdd(&statsOut[rep * 128 + tid],      sums[tid]);
            atomicAdd(&statsOut[rep * 128 + 64 + tid], sqs[tid]);
        }
    }
}

// ---------------------------------------------------------------------------
// FUSED L2 v5: 128-row tiles, grid 1024, 4 blocks/CU (LDS 39424, VGPR<=128).
//   r9: tap batches of 8 (was 4) -> 8 serial load-stops/thread instead of 16;
//   v[8] = 32 VGPRs in flight. Tap order 0..15 preserved -> bit-identical.
// ---------------------------------------------------------------------------
__global__ __launch_bounds__(256, 4) void gemm2_fused(
    const bf16* __restrict__ y1, const bf16* __restrict__ WT,
    const float* __restrict__ st, const float* __restrict__ gam,
    const float* __restrict__ bet, const float* __restrict__ k2T,
    const float* __restrict__ bias, bf16* __restrict__ y,
    float* __restrict__ statsOut)
{
    constexpr int SK = 68;                      // 128*68*2 shorts = 34816 B A+B
    constexpr int CS = 136;
    __shared__ __align__(16) unsigned short smem[17408];   // 34816 B
    unsigned short* As  = smem;                 // 128*68 = 8704 shorts
    unsigned short* Bs  = smem + 8704;          // 128*68 = 8704 shorts
    unsigned short* Csh = smem;                 // 128*136 = 17408 shorts (overlay)
    __shared__ __align__(16) float extra[1024]; // klds during staging
    float* klds = extra;                        // [tap][c], 4 KB
    float* sums = extra;                        // overlay: klds dead by then
    float* sqs  = extra + 128;
    __shared__ float scL[64], shL[64];

    const int tid  = threadIdx.x;
    const int lane = tid & 63;
    const int w    = tid >> 6;
    const int wm   = (w >> 1) * 64, wn = (w & 1) * 64;
    const int lm   = lane & 15, lq = lane >> 4;
    const long m0  = (long)blockIdx.x * 128;
    const int  b   = (int)(m0 >> 10);         // sample index (1024 px/sample)

    *(float4*)&klds[tid * 4] = *(const float4*)&k2T[b * 1024 + tid * 4];
    if (tid < 64) {                            // folded bn_prep (C=64)
        float s = 0.f, q = 0.f;
        #pragma unroll
        for (int r = 0; r < NREP; ++r) {
            s += st[r * 128 + tid];
            q += st[r * 128 + 64 + tid];
        }
        const float NINV = 1.f / 524288.f;
        float m   = s * NINV;
        float var = fmaf(q, NINV, -m * m);
        float sc  = gam[tid] * rsqrtf(var + 1e-5f);
        scL[tid] = sc;
        shL[tid] = fmaf(-m, sc, bet[tid]);
    }
    #pragma unroll
    for (int s = 0; s < 4; ++s) {
        int i = tid + s * 256;                // 1024 granules of B (128 rows x 8)
        int n = i >> 3, q = i & 7;
        uint4 vb = *(const uint4*)(WT + (long)n * 64 + q * 8);
        *(uint4*)&Bs[n * SK + q * 8] = vb;
    }
    __syncthreads();

    // A staging with fused depthwise conv: 128 rows x 8 granules = 1024 items.
    // Item loop unroll-1; taps in 2 batches of 8 (8 load-stops/thread total).
    #pragma unroll 1
    for (int s = 0; s < 4; ++s) {
        int i = tid + s * 256;
        int m = i >> 3, q = i & 7;
        int pos = (int)((m0 + m) & 1023);
        int oy = pos >> 5, ox = pos & 31;
        int c0 = q * 8;
        int iy0 = oy * 2 - 1, ix0 = ox * 2 - 1;

        float sc[8], sh[8];
        #pragma unroll
        for (int ch = 0; ch < 8; ++ch) { sc[ch] = scL[c0 + ch]; sh[ch] = shL[c0 + ch]; }

        float acc[8];
        #pragma unroll
        for (int ch = 0; ch < 8; ++ch) acc[ch] = 0.f;

        #pragma unroll 1
        for (int t0 = 0; t0 < 16; t0 += 8) {
            uint4 v[8];
            #pragma unroll
            for (int u = 0; u < 8; ++u) {
                int t  = t0 + u;
                int iy = iy0 + (t >> 2), ix = ix0 + (t & 3);
                int iyc = min(max(iy, 0), 63), ixc = min(max(ix, 0), 63);
                v[u] = *(const uint4*)&y1[((long)(b * 64 + iyc) * 64 + ixc) * 64 + c0];
            }
            #pragma unroll
            for (int u = 0; u < 8; ++u) {
                int t  = t0 + u;
                int iy = iy0 + (t >> 2), ix = ix0 + (t & 3);
                bool ok = ((unsigned)iy < 64u) && ((unsigned)ix < 64u);
                float4 wa = *(const float4*)&klds[t * 64 + c0];
                float4 wb = *(const float4*)&klds[t * 64 + c0 + 4];
                const float wt[8] = {wa.x, wa.y, wa.z, wa.w, wb.x, wb.y, wb.z, wb.w};
                #pragma unroll
                for (int ch = 0; ch < 8; ++ch) {
                    unsigned uu = ((const unsigned*)&v[u])[ch >> 1];
                    unsigned bits = (ch & 1) ? (uu & 0xffff0000u) : (uu << 16);
                    float xb = ok ? fmaf(__uint_as_float(bits), sc[ch], sh[ch]) : 0.f;
                    acc[ch] = fmaf(xb, wt[ch], acc[ch]);
                }
            }
        }
        union { uint4 u4; unsigned short us[8]; } pk;
        #pragma unroll
        for (int ch = 0; ch < 8; ++ch) pk.us[ch] = f2b(acc[ch]);
        *(uint4*)&As[m * SK + q * 8] = pk.u4;
    }
    __syncthreads();

    floatx4 acc[4][4];
    #pragma unroll
    for (int i = 0; i < 4; ++i)
        #pragma unroll
        for (int j = 0; j < 4; ++j) acc[i][j] = (floatx4)0.0f;
    #pragma unroll
    for (int h = 0; h < 2; ++h) {
        short8 af[4], bfr[4];
        #pragma unroll
        for (int i = 0; i < 4; ++i) {
            af[i]  = *(const short8*)&As[(wm + i * 16 + lm) * SK + h * 32 + lq * 8];
            bfr[i] = *(const short8*)&Bs[(wn + i * 16 + lm) * SK + h * 32 + lq * 8];
        }
        #pragma unroll
        for (int i = 0; i < 4; ++i)
            #pragma unroll
            for (int j = 0; j < 4; ++j)
                acc[i][j] = __builtin_amdgcn_mfma_f32_16x16x32_bf16(af[i], bfr[j], acc[i][j], 0, 0, 0);
    }
    __syncthreads();

    float bj[4];
    #pragma unroll
    for (int j = 0; j < 4; ++j) bj[j] = bias[wn + j * 16 + lm];

    if (tid < 128) { sums[tid] = 0.f; sqs[tid] = 0.f; }   // klds region, dead
    #pragma unroll
    for (int i = 0; i < 4; ++i)
        #pragma unroll
        for (int j = 0; j < 4; ++j) {
            int c = wn + j * 16 + lm;
            #pragma unroll
            for (int rg = 0; rg < 4; ++rg) {
                int r = wm + i * 16 + lq * 4 + rg;
                float v = acc[i][j][rg] + bj[j];
                v = v > 0.f ? v : 0.2f * v;
                Csh[r * CS + c] = f2b(v);
            }
        }
    __syncthreads();
    {
        const int cg = tid & 15, mr = tid >> 4;
        float sacc[8], qacc[8];
        #pragma unroll
        for (int t = 0; t < 8; ++t) { sacc[t] = 0.f; qacc[t] = 0.f; }
        #pragma unroll
        for (int it = 0; it < 8; ++it) {
            int m = mr + it * 16;
            uint4 pk = *(const uint4*)&Csh[m * CS + cg * 8];
            *(uint4*)&y[(m0 + m) * 128 + cg * 8] = pk;
            const unsigned short* pu = (const unsigned short*)&pk;
            #pragma unroll
            for (int t = 0; t < 8; ++t) {
                float f = b2f(pu[t]);
                sacc[t] += f;
                qacc[t] = fmaf(f, f, qacc[t]);
            }
        }
        #pragma unroll
        for (int t = 0; t < 8; ++t) {
            atomicAdd(&sums[cg * 8 + t], sacc[t]);
            atomicAdd(&sqs [cg * 8 + t], qacc[t]);
        }
    }
    __syncthreads();
    {
        const int rep = blockIdx.x & (NREP - 1);
        if (tid < 128) {
            atomicAdd(&statsOut[rep * 256 + tid],        sums[tid]);
            atomicAdd(&statsOut[rep * 256 + 128 + tid],  sqs[tid]);
        }
    }
}

// ---------------------------------------------------------------------------
// Direct-tap depthwise conv (layers 3..5): thread = (output pixel, 8 ch).
// BN affine computed in-kernel from the previous layer's stats replicas.
// ---------------------------------------------------------------------------
template<int C, int KS, int HIN, int HOUT, int STRIDE, int PAD, int NTHR>
__global__ __launch_bounds__(NTHR) void dw_direct(
    const bf16* __restrict__ x, const float* __restrict__ st,
    const float* __restrict__ gam, const float* __restrict__ bet,
    float NINV, const float* __restrict__ dynkT, bf16* __restrict__ outA)
{
    constexpr int G   = C / 8;
    constexpr int KSK = KS * KS;
    static_assert(NTHR == HOUT * G, "one output row per block");

    __shared__ __align__(16) float wlds[KSK * C];
    __shared__ float affs[2 * C];

    const int tid = threadIdx.x;
    const int b   = blockIdx.x / HOUT;
    const int oy  = blockIdx.x % HOUT;

    {
        const float* src = dynkT + (long)b * (KSK * C);
        for (int i = tid * 4; i < KSK * C; i += NTHR * 4)
            *(float4*)&wlds[i] = *(const float4*)&src[i];
    }
    for (int c = tid; c < C; c += NTHR) {     // folded bn_prep
        float s = 0.f, q = 0.f;
        #pragma unroll
        for (int r = 0; r < NREP; ++r) {
            s += st[r * 2 * C + c];
            q += st[r * 2 * C + C + c];
        }
        float m   = s * NINV;
        float var = fmaf(q, NINV, -m * m);
        float sc  = gam[c] * rsqrtf(var + 1e-5f);
        affs[c]     = sc;
        affs[C + c] = fmaf(-m, sc, bet[c]);
    }
    __syncthreads();

    const int g  = tid % G;
    const int ox = tid / G;
    const int c0 = g * 8;
    const int iy0 = oy * STRIDE - PAD;
    const int ix0 = ox * STRIDE - PAD;

    float sc[8], sh[8];
    #pragma unroll
    for (int ch = 0; ch < 8; ++ch) {
        sc[ch] = affs[c0 + ch];
        sh[ch] = affs[C + c0 + ch];
    }

    float acc[8];
    #pragma unroll
    for (int ch = 0; ch < 8; ++ch) acc[ch] = 0.f;

    const bool interior = (iy0 >= 0) && (iy0 + KS <= HIN) &&
                          (ix0 >= 0) && (ix0 + KS <= HIN);

    if (interior) {
        const bf16* bp = x + ((long)(b * HIN + iy0) * HIN + ix0) * C + c0;
        uint4 v[KSK];
        #pragma unroll
        for (int kh = 0; kh < KS; ++kh)
            #pragma unroll
            for (int kw = 0; kw < KS; ++kw)
                v[kh * KS + kw] = *(const uint4*)(bp + (kh * HIN + kw) * C);
        #pragma unroll
        for (int t = 0; t < KSK; ++t) {
            const float* wp = &wlds[t * C + c0];
            float4 wa = *(const float4*)wp;
            float4 wb = *(const float4*)(wp + 4);
            const float wt[8] = {wa.x, wa.y, wa.z, wa.w, wb.x, wb.y, wb.z, wb.w};
            #pragma unroll
            for (int ch = 0; ch < 8; ++ch) {
                unsigned u = ((const unsigned*)&v[t])[ch >> 1];
                unsigned bits = (ch & 1) ? (u & 0xffff0000u) : (u << 16);
                float xb = fmaf(__uint_as_float(bits), sc[ch], sh[ch]);
                acc[ch] = fmaf(xb, wt[ch], acc[ch]);
            }
        }
    } else {
        #pragma unroll
        for (int kh = 0; kh < KS; ++kh) {
            const int iy = iy0 + kh;
            if ((unsigned)iy >= (unsigned)HIN) continue;
            #pragma unroll
            for (int kw = 0; kw < KS; ++kw) {
                const int ix = ix0 + kw;
                if ((unsigned)ix >= (unsigned)HIN) continue;
                uint4 v = *(const uint4*)&x[((long)(b * HIN + iy) * HIN + ix) * C + c0];
                const float* wp = &wlds[(kh * KS + kw) * C + c0];
                float4 wa = *(const float4*)wp;
                float4 wb = *(const float4*)(wp + 4);
                const float wt[8] = {wa.x, wa.y, wa.z, wa.w, wb.x, wb.y, wb.z, wb.w};
                #pragma unroll
                for (int ch = 0; ch < 8; ++ch) {
                    unsigned u = ((const unsigned*)&v)[ch >> 1];
                    unsigned bits = (ch & 1) ? (u & 0xffff0000u) : (u << 16);
                    float xb = fmaf(__uint_as_float(bits), sc[ch], sh[ch]);
                    acc[ch] = fmaf(xb, wt[ch], acc[ch]);
                }
            }
        }
    }

    union { uint4 v; unsigned short us[8]; } pk;
    #pragma unroll
    for (int ch = 0; ch < 8; ++ch) pk.us[ch] = f2b(acc[ch]);
    *(uint4*)&outA[((long)(b * HOUT + oy) * HOUT + ox) * C + c0] = pk.v;
}

// ---------------------------------------------------------------------------
// MFMA bf16 GEMM: C[M,COUT] = A[M,K] x W[K,COUT], 128x128 block tile, BK=64.
// ---------------------------------------------------------------------------
template<int K, int COUT, bool LAST>
__global__ __launch_bounds__(256) void gemm_layer(
    const bf16* __restrict__ A, const bf16* __restrict__ WT,
    const float* __restrict__ bias, bf16* __restrict__ y,
    float* __restrict__ statsOut, float* __restrict__ outF, int Mtiles)
{
    constexpr int SK = 72;
    constexpr int CS = 136;
    __shared__ __align__(16) unsigned short smem[18432];
    unsigned short* As  = smem;
    unsigned short* Bs  = smem + 9216;
    unsigned short* Csh = smem;
    __shared__ float sums[128], sqs[128];

    const int tid  = threadIdx.x;
    const int lane = tid & 63;
    const int w    = tid >> 6;
    const int wm   = (w >> 1) * 64, wn = (w & 1) * 64;
    const int lm   = lane & 15, lq = lane >> 4;
    const int mt   = blockIdx.x % Mtiles;
    const int nt   = blockIdx.x / Mtiles;
    const long m0  = (long)mt * 128;
    const int  n0  = nt * 128;

    floatx4 acc[4][4];
    #pragma unroll
    for (int i = 0; i < 4; ++i)
        #pragma unroll
        for (int j = 0; j < 4; ++j) acc[i][j] = (floatx4)0.0f;

    for (int kb = 0; kb < K; kb += 64) {
        __syncthreads();
        #pragma unroll
        for (int s = 0; s < 4; ++s) {
            int i = tid + s * 256;
            int m = i >> 3, q = i & 7;
            uint4 va = *(const uint4*)(A  + ((m0 + m) * K + kb + q * 8));
            uint4 vb = *(const uint4*)(WT + ((long)(n0 + m) * K + kb + q * 8));
            *(uint4*)&As[m * SK + q * 8] = va;
            *(uint4*)&Bs[m * SK + q * 8] = vb;
        }
        __syncthreads();
        #pragma unroll
        for (int h = 0; h < 2; ++h) {
            short8 af[4], bfr[4];
            #pragma unroll
            for (int i = 0; i < 4; ++i) {
                af[i]  = *(const short8*)&As[(wm + i * 16 + lm) * SK + h * 32 + lq * 8];
                bfr[i] = *(const short8*)&Bs[(wn + i * 16 + lm) * SK + h * 32 + lq * 8];
            }
            #pragma unroll
            for (int i = 0; i < 4; ++i)
                #pragma unroll
                for (int j = 0; j < 4; ++j)
                    acc[i][j] = __builtin_amdgcn_mfma_f32_16x16x32_bf16(af[i], bfr[j], acc[i][j], 0, 0, 0);
        }
    }
    __syncthreads();

    float bj[4];
    #pragma unroll
    for (int j = 0; j < 4; ++j) bj[j] = bias[n0 + wn + j * 16 + lm];

    if constexpr (!LAST) {
        if (tid < 128) { sums[tid] = 0.f; sqs[tid] = 0.f; }
        #pragma unroll
        for (int i = 0; i < 4; ++i)
            #pragma unroll
            for (int j = 0; j < 4; ++j) {
                int c = wn + j * 16 + lm;
                #pragma unroll
                for (int rg = 0; rg < 4; ++rg) {
                    int r = wm + i * 16 + lq * 4 + rg;
                    float v = acc[i][j][rg] + bj[j];
                    v = v > 0.f ? v : 0.2f * v;
                    Csh[r * CS + c] = f2b(v);
                }
            }
        __syncthreads();
        const int cg = tid & 15, mr = tid >> 4;
        float sacc[8], qacc[8];
        #pragma unroll
        for (int t = 0; t < 8; ++t) { sacc[t] = 0.f; qacc[t] = 0.f; }
        #pragma unroll
        for (int it = 0; it < 8; ++it) {
            int m = mr + it * 16;
            uint4 pk = *(const uint4*)&Csh[m * CS + cg * 8];
            *(uint4*)&y[(m0 + m) * COUT + n0 + cg * 8] = pk;
            const unsigned short* pu = (const unsigned short*)&pk;
            #pragma unroll
            for (int t = 0; t < 8; ++t) {
                float f = b2f(pu[t]);
                sacc[t] += f;
                qacc[t] = fmaf(f, f, qacc[t]);
            }
        }
        #pragma unroll
        for (int t = 0; t < 8; ++t) {
            atomicAdd(&sums[cg * 8 + t], sacc[t]);
            atomicAdd(&sqs [cg * 8 + t], qacc[t]);
        }
        __syncthreads();
        {
            const int rep = blockIdx.x & (NREP - 1);
            if (tid < 128) {
                atomicAdd(&statsOut[rep * 2 * COUT + n0 + tid],        sums[tid]);
                atomicAdd(&statsOut[rep * 2 * COUT + COUT + n0 + tid], sqs[tid]);
            }
        }
    } else {
        #pragma unroll
        for (int i = 0; i < 4; ++i)
            #pragma unroll
            for (int j = 0; j < 4; ++j) {
                int c  = wn + j * 16 + lm;
                int rb = wm + i * 16 + lq * 4;
                ushort4 pk;
                unsigned short* pp = (unsigned short*)&pk;
                #pragma unroll
                for (int rg = 0; rg < 4; ++rg)
                    pp[rg] = f2b(acc[i][j][rg] + bj[j]);
                *(ushort4*)&Csh[c * CS + rb] = pk;
            }
        __syncthreads();
        const int mg = tid & 15, nr = tid >> 4;
        #pragma unroll
        for (int it = 0; it < 8; ++it) {
            int n = nr + it * 16;
            uint4 pk = *(const uint4*)&Csh[n * CS + mg * 8];
            const unsigned short* pu = (const unsigned short*)&pk;
            #pragma unroll
            for (int t = 0; t < 8; ++t) {
                int m = (int)m0 + mg * 8 + t;
                int b = m / 49, pos = m - b * 49;
                float v = b2f(pu[t]);
                outF[((long)(b * 512 + n0 + n)) * 49 + pos] = 1.f / (1.f + __expf(-v));
            }
        }
    }
}

// ---------------------------------------------------------------------------

extern "C" void kernel_launch(void* const* d_in, const int* in_sizes, int n_in,
                              void* d_out, int out_size, void* d_ws, size_t ws_size,
                              hipStream_t stream)
{
    const float* input = (const float*)d_in[0];
    const int*   label = (const int*)d_in[1];
    const float* emb   = (const float*)d_in[2];
    const float* lw[5] = {(const float*)d_in[3], (const float*)d_in[5], (const float*)d_in[7],
                          (const float*)d_in[9], (const float*)d_in[11]};
    const float* lb[5] = {(const float*)d_in[4], (const float*)d_in[6], (const float*)d_in[8],
                          (const float*)d_in[10], (const float*)d_in[12]};
    const float* cmw[5] = {(const float*)d_in[13], (const float*)d_in[15], (const float*)d_in[17],
                           (const float*)d_in[19], (const float*)d_in[21]};
    const float* cmb[5] = {(const float*)d_in[14], (const float*)d_in[16], (const float*)d_in[18],
                           (const float*)d_in[20], (const float*)d_in[22]};
    const float* bng[4] = {(const float*)d_in[23], (const float*)d_in[25],
                           (const float*)d_in[27], (const float*)d_in[29]};
    const float* bnb[4] = {(const float*)d_in[24], (const float*)d_in[26],
                           (const float*)d_in[28], (const float*)d_in[30]};
    float* out = (float*)d_out;

    float* wsf   = (float*)d_ws;
    float* dynk  = wsf;
    float* stats = wsf + 1071104;
    const float* k1  = dynk;
    const float* k2T = dynk + 6144;
    const float* k3T = dynk + 137216;
    const float* k4T = dynk + 284672;
    const float* k5T = dynk + 808960;
    float* st1 = stats;
    float* st2 = stats + 2048;
    float* st3 = stats + 6144;
    float* st4 = stats + 14336;

    bf16* wt  = (bf16*)((char*)d_ws + 4407296);
    bf16* wt2 = wt;
    bf16* wt3 = wt + 8192;
    bf16* wt4 = wt + 40960;
    bf16* wt5 = wt + 172032;
    bf16* S1  = (bf16*)((char*)d_ws + 5308416);    // 33554432 elems capacity
    bf16* S2  = (bf16*)((char*)d_ws + 72417280);   // y2: 16777216 elems (33.5 MB)

    // S1 sub-regions for the L3..L5 chain (elems; y1 dead after gemm2_fused).
    // Sizes: A3 4194304 | y3 8388608 | A4 2097152 | y4 4194304 | A5 3211264.
    bf16* A3 = S1;                   // ends  4194304
    bf16* y3 = S1 + 4194304;         // ends 12582912
    bf16* A4 = S1 + 12582912;        // ends 14680064
    bf16* y4 = S1 + 14680064;        // ends 18874368
    bf16* A5 = S1 + 18874368;        // ends 22085632 < 33554432

    // Merged head: prep (4186 blocks) + wt (424 blocks) in one dispatch.
    prep_wt_kernel<<<4610, 256, 0, stream>>>(label, emb,
        lw[0], lb[0], lw[1], lb[1], lw[2], lb[2], lw[3], lb[3], lw[4], lb[4],
        dynk, stats, out + 3211264,
        cmw[1], cmw[2], cmw[3], cmw[4], wt2, wt3, wt4, wt5);

    // L1: fused (K=3) -> y1 @ S1 + st1
    fused_l1_v6<<<2048, 256, 0, stream>>>(input, k1, cmw[0], cmb[0], S1, st1);

    // L2: dw fused into gemm A-staging (128-row tiles, 4/CU); bn1 in-kernel.
    gemm2_fused<<<1024, 256, 0, stream>>>(S1, wt2, st1, bng[0], bnb[0],
                                          k2T, cmb[1], S2, st2);

    // L3: y2 (S2) -> A3 (S1) -> y3; bn2 affine in-kernel.
    dw_direct<128, 3, 32, 16, 2, 1, 256><<<2048, 256, 0, stream>>>(
        S2, st2, bng[1], bnb[1], 1.f / 131072.f, k3T, A3);
    gemm_layer<128, 256, false><<<512, 256, 0, stream>>>(
        A3, wt3, cmb[2], y3, st3, nullptr, 256);

    // L4: y3 -> A4 -> y4; bn3 affine in-kernel.
    dw_direct<256, 4, 16, 8, 2, 1, 256><<<1024, 256, 0, stream>>>(
        y3, st3, bng[2], bnb[2], 1.f / 32768.f, k4T, A4);
    gemm_layer<256, 512, false><<<256, 256, 0, stream>>>(
        A4, wt4, cmb[3], y4, st4, nullptr, 64);

    // L5: y4 -> A5 -> out; bn4 affine in-kernel.
    dw_direct<512, 2, 8, 7, 1, 0, 448><<<896, 448, 0, stream>>>(
        y4, st4, bng[3], bnb[3], 1.f / 8192.f, k5T, A5);
    gemm_layer<512, 512, true><<<196, 256, 0, stream>>>(
        A5, wt5, cmb[4], nullptr, nullptr, out, 49);
}

// Round 15
// 305.057 us; speedup vs baseline: 1.0166x; 1.0166x over previous
//
#include <hip/hip_runtime.h>
#include <hip/hip_bf16.h>

typedef __hip_bfloat16 bf16;
using short8  = __attribute__((ext_vector_type(8))) short;
using floatx4 = __attribute__((ext_vector_type(4))) float;

__device__ __forceinline__ float b2f(unsigned short u) {
    union { unsigned int i; float f; } v; v.i = ((unsigned int)u) << 16; return v.f;
}
__device__ __forceinline__ unsigned short f2b(float f) {
    bf16 h = __float2bfloat16(f);
    return *(unsigned short*)&h;
}

// ---------------------------------------------------------------------------
// Workspace layout (bytes) -- NON-OVERLAPPING:
//   dynk  @ 0         : fp32 (k1 6144 | k2T 131072 | k3T 147456 | k4T 524288 | k5T 262144 els)
//   stats @ 4284416   : 30720 fp32, 16 replicas per layer -> ends 4407296
//   WT    @ 4407296   : bf16 -> ends 5275648
//   S1    @ 5308416   : bf16, 33554432 elems. y1 during L1/L2; then A3/y3/A4/y4/A5.
//   S2    @ 72417280  : bf16, y2 = 16777216 elems (33.5 MB)
//
// MEASURED THIS SESSION:
//   r4:  gemm_dw L3-L5 fusion REGRESSION -> reverted. gemm2 128row=68.4us.
//   r5:  64-row split REGRESSION (100.1us; VGPR cliff at 128 identified).
//   r6:  launch_bounds(256,4) not honored w/ full-unroll staging; LDS 41472
//        also capped 3/CU. total 320.8.
//   r8:  SK=68 (LDS 39424) + unroll-1 batch-4 -> VGPR 64, occ 28%, gemm2
//        55.9us, TOTAL 308.5 (best).
//   r11: batch-8 NEUTRAL/worse (57.4us, VGPR still 64) -> serial-latency
//        theory REFUTED; staging is load-VOLUME bound.
//   r12-r15 (queued, broker down): pixel-PAIR staging -- (even,odd) px share
//        2 of 4 input cols: 24 loads/2px (-25%), klds tap reads shared
//        (-50%). Tap order 0..15 per px preserved -> bit-identical. Predict
//        dur 47-52, VGPR <= 96; if dur >= 55 PIVOT off gemm2.
// HARD-WON RULES (session 1): disjoint ws regions WITH sizes; no threadfence
//   in wide epilogues; fusion only where it doesn't duplicate work.
// ---------------------------------------------------------------------------
#define NREP 16

// Merged head kernel: blocks 0..4185 = dyn-kernel prep (block 4185 also does
// housekeeping); blocks 4186..4609 = weight transpose-convert.
__global__ __launch_bounds__(256) void prep_wt_kernel(
    const int* __restrict__ label, const float* __restrict__ emb,
    const float* __restrict__ l1w, const float* __restrict__ l1b,
    const float* __restrict__ l2w, const float* __restrict__ l2b,
    const float* __restrict__ l3w, const float* __restrict__ l3b,
    const float* __restrict__ l4w, const float* __restrict__ l4b,
    const float* __restrict__ l5w, const float* __restrict__ l5b,
    float* __restrict__ dynk, float* __restrict__ stats,
    float* __restrict__ labelOut,
    const float* __restrict__ w2, const float* __restrict__ w3,
    const float* __restrict__ w4, const float* __restrict__ w5,
    bf16* __restrict__ wt2, bf16* __restrict__ wt3,
    bf16* __restrict__ wt4, bf16* __restrict__ wt5)
{
    __shared__ float T[32][33];
    const int tid = threadIdx.x;

    if (blockIdx.x >= 4186) {                            // ---- wt path ----
        int t = blockIdx.x - 4186;
        const float* W; bf16* WT; int K, N, tl;
        if (t < 8)        { W = w2; WT = wt2; K = 64;  N = 128; tl = t; }
        else if (t < 40)  { W = w3; WT = wt3; K = 128; N = 256; tl = t - 8; }
        else if (t < 168) { W = w4; WT = wt4; K = 256; N = 512; tl = t - 40; }
        else              { W = w5; WT = wt5; K = 512; N = 512; tl = t - 168; }
        const int NT = N >> 5;
        const int kt = tl / NT, nt = tl - kt * NT;
        const int k0 = kt * 32, n0 = nt * 32;
        const int cc = tid & 31, rr = tid >> 5;
        #pragma unroll
        for (int it = 0; it < 4; ++it) {
            int k = rr + it * 8;
            T[k][cc] = W[(long)(k0 + k) * N + n0 + cc];
        }
        __syncthreads();
        #pragma unroll
        for (int it = 0; it < 4; ++it) {
            int n = rr + it * 8;
            WT[(long)(n0 + n) * K + k0 + cc] = __float2bfloat16(T[cc][n]);
        }
        return;
    }

    if (blockIdx.x == 4185) {                            // housekeeping block
        for (int i = tid; i < 30720; i += 256) stats[i] = 0.0f;
        if (tid < 128) labelOut[tid] = (float)label[tid];
        return;
    }

    int idx = blockIdx.x * 256 + tid;                    // ---- prep path ----
    if (idx >= 1071104) return;
    const float* w; const float* bb; int loc, ckk, ksk, base;
    if (idx < 6144)        { w = l1w; bb = l1b; loc = idx;          ckk = 48;   ksk = 0;  base = 0;      }
    else if (idx < 137216) { w = l2w; bb = l2b; loc = idx - 6144;   ckk = 1024; ksk = 16; base = 6144;   }
    else if (idx < 284672) { w = l3w; bb = l3b; loc = idx - 137216; ckk = 1152; ksk = 9;  base = 137216; }
    else if (idx < 808960) { w = l4w; bb = l4b; loc = idx - 284672; ckk = 4096; ksk = 16; base = 284672; }
    else                   { w = l5w; bb = l5b; loc = idx - 808960; ckk = 2048; ksk = 4;  base = 808960; }
    int b   = loc / ckk;
    int col = loc - b * ckk;
    int lab = label[b];
    float acc = bb[col];
    #pragma unroll
    for (int m = 0; m < 5; ++m)
        acc = fmaf(emb[lab * 5 + m], w[m * ckk + col], acc);
    float val = tanhf(acc);
    if (ksk == 0) {
        dynk[idx] = val;                          // layer 1: [b][c*k*k]
    } else {
        int c  = col / ksk;                       // transposed: [b][tap][c]
        int t  = col - c * ksk;
        int Cl = ckk / ksk;
        dynk[base + b * ckk + t * Cl + c] = val;
    }
}

// ---------------------------------------------------------------------------
// Layer 1 v6: 32w x 8h tile per block, 256 threads, 2048 blocks, ~20 KB LDS.
// ---------------------------------------------------------------------------
__global__ __launch_bounds__(256) void fused_l1_v6(
    const float* __restrict__ xf, const float* __restrict__ dynk,
    const float* __restrict__ W, const float* __restrict__ bias,
    bf16* __restrict__ y, float* __restrict__ statsOut)
{
    constexpr int HIN = 128, HOUT = 64;
    constexpr int TW = 32, TH = 8;
    constexpr int PS  = 68;
    constexpr int PCH = 18 * PS;

    __shared__ float patch[3 * PCH];
    __shared__ __align__(16) float dwT[32 * 28];
    __shared__ float Wlds[192];
    __shared__ float klds[48];
    __shared__ float biasL[64];
    __shared__ float sums[64], sqs[64];

    const int tid = threadIdx.x;
    const int b   = blockIdx.x >> 4;
    const int tl  = blockIdx.x & 15;
    const int ty0 = (tl >> 1) * TH;
    const int tx0 = (tl & 1) * TW;

    if (tid < 48) klds[tid] = dynk[b * 48 + tid];
    if (tid >= 64 && tid < 256) Wlds[tid - 64] = W[tid - 64];
    if (tid < 64) { biasL[tid] = bias[tid]; sums[tid] = 0.f; sqs[tid] = 0.f; }

    {
        const int iy0 = ty0 * 2 - 1, ix0 = tx0 * 2 - 1;
        #pragma unroll
        for (int k = 0; k < 15; ++k) {
            int i  = tid + k * 256;
            int c  = i / 1224;
            int r  = i - c * 1224;
            int py = r / 68, px = r - py * 68;
            int gy = iy0 + py, gx = ix0 + px;
            bool slot = (i < 3672);
            bool inb  = slot && (px < 66) &&
                        ((unsigned)gy < (unsigned)HIN) && ((unsigned)gx < (unsigned)HIN);
            float v = 0.f;
            if (inb) v = xf[((long)b * 3 + c) * (HIN * HIN) + gy * HIN + gx];
            if (slot) patch[c * PCH + py * PS + px] = v;
        }
    }
    __syncthreads();

    {
        const int py = tid >> 5, px = tid & 31;
        const int pixg = tid >> 3, j = tid & 7;
        #pragma unroll
        for (int c = 0; c < 3; ++c) {
            const float* pb = &patch[c * PCH + (py * 2) * PS + px * 2];
            float a = 0.f;
            #pragma unroll
            for (int kh = 0; kh < 4; ++kh)
                #pragma unroll
                for (int kw = 0; kw < 4; ++kw)
                    a = fmaf(pb[kh * PS + kw], klds[c * 16 + kh * 4 + kw], a);
            dwT[pixg * 28 + j * 3 + c] = a;
        }
    }
    __syncthreads();

    {
        const int cq = tid & 7, pixg = tid >> 3;
        const int d0 = cq * 8;
        float Wr[3][8], bi[8];
        #pragma unroll
        for (int c = 0; c < 3; ++c)
            #pragma unroll
            for (int t = 0; t < 8; ++t) Wr[c][t] = Wlds[c * 64 + d0 + t];
        #pragma unroll
        for (int t = 0; t < 8; ++t) bi[t] = biasL[d0 + t];

        float dv[24];
        #pragma unroll
        for (int q4 = 0; q4 < 6; ++q4)
            *(float4*)&dv[q4 * 4] = *(const float4*)&dwT[pixg * 28 + q4 * 4];

        float sreg[8] = {}, qreg[8] = {};
        #pragma unroll
        for (int j = 0; j < 8; ++j) {
            const int pos = pixg * 8 + j;
            const float dv0 = dv[j * 3 + 0];
            const float dv1 = dv[j * 3 + 1];
            const float dv2 = dv[j * 3 + 2];
            const int py = pos >> 5, px = pos & 31;
            const long row = ((long)(b * HOUT + ty0 + py)) * HOUT + tx0 + px;
            union { uint4 v; unsigned short us[8]; } pk;
            #pragma unroll
            for (int t = 0; t < 8; ++t) {
                float v = fmaf(dv0, Wr[0][t], fmaf(dv1, Wr[1][t], fmaf(dv2, Wr[2][t], bi[t])));
                v = v > 0.f ? v : 0.2f * v;
                sreg[t] += v;
                qreg[t] = fmaf(v, v, qreg[t]);
                pk.us[t] = f2b(v);
            }
            *(uint4*)&y[row * 64 + d0] = pk.v;
        }
        #pragma unroll
        for (int m = 8; m < 64; m <<= 1)
            #pragma unroll
            for (int t = 0; t < 8; ++t) {
                sreg[t] += __shfl_xor(sreg[t], m);
                qreg[t] += __shfl_xor(qreg[t], m);
            }
        if ((tid & 63) < 8) {
            #pragma unroll
            for (int t = 0; t < 8; ++t) {
                atomicAdd(&sums[d0 + t], sreg[t]);
                atomicAdd(&sqs [d0 + t], qreg[t]);
            }
        }
    }
    __syncthreads();
    {
        const int rep = blockIdx.x & (NREP - 1);
        if (tid < 64) {
            atomicAdd(&statsOut[rep * 128 + tid],      sums[tid]);
            atomicAdd(&statsOut[rep * 128 + 64 + tid], sqs[tid]);
        }
    }
}

// ---------------------------------------------------------------------------
// FUSED L2 v6: 128-row tiles, grid 1024, 4 blocks/CU (LDS 39424).
//   r12: pixel-PAIR dw staging. Adjacent (even,odd) output px share input
//   cols: per pair 4 rows x 6 cols = 24 loads (vs 32); klds reads shared.
//   Per-pixel tap order 0..15 (kh-major) preserved -> bit-identical.
// ---------------------------------------------------------------------------
__global__ __launch_bounds__(256, 4) void gemm2_fused(
    const bf16* __restrict__ y1, const bf16* __restrict__ WT,
    const float* __restrict__ st, const float* __restrict__ gam,
    const float* __restrict__ bet, const float* __restrict__ k2T,
    const float* __restrict__ bias, bf16* __restrict__ y,
    float* __restrict__ statsOut)
{
    constexpr int SK = 68;                      // 128*68*2 shorts = 34816 B A+B
    constexpr int CS = 136;
    __shared__ __align__(16) unsigned short smem[17408];   // 34816 B
    unsigned short* As  = smem;                 // 128*68 = 8704 shorts
    unsigned short* Bs  = smem + 8704;          // 128*68 = 8704 shorts
    unsigned short* Csh = smem;                 // 128*136 = 17408 shorts (overlay)
    __shared__ __align__(16) float extra[1024]; // klds during staging
    float* klds = extra;                        // [tap][c], 4 KB
    float* sums = extra;                        // overlay: klds dead by then
    float* sqs  = extra + 128;
    __shared__ float scL[64], shL[64];

    const int tid  = threadIdx.x;
    const int lane = tid & 63;
    const int w    = tid >> 6;
    const int wm   = (w >> 1) * 64, wn = (w & 1) * 64;
    const int lm   = lane & 15, lq = lane >> 4;
    const long m0  = (long)blockIdx.x * 128;
    const int  b   = (int)(m0 >> 10);         // sample index (1024 px/sample)

    *(float4*)&klds[tid * 4] = *(const float4*)&k2T[b * 1024 + tid * 4];
    if (tid < 64) {                            // folded bn_prep (C=64)
        float s = 0.f, q = 0.f;
        #pragma unroll
        for (int r = 0; r < NREP; ++r) {
            s += st[r * 128 + tid];
            q += st[r * 128 + 64 + tid];
        }
        const float NINV = 1.f / 524288.f;
        float m   = s * NINV;
        float var = fmaf(q, NINV, -m * m);
        float sc  = gam[tid] * rsqrtf(var + 1e-5f);
        scL[tid] = sc;
        shL[tid] = fmaf(-m, sc, bet[tid]);
    }
    #pragma unroll
    for (int s = 0; s < 4; ++s) {
        int i = tid + s * 256;                // 1024 granules of B (128 rows x 8)
        int n = i >> 3, q = i & 7;
        uint4 vb = *(const uint4*)(WT + (long)n * 64 + q * 8);
        *(uint4*)&Bs[n * SK + q * 8] = vb;
    }
    __syncthreads();

    // A staging with fused depthwise conv, PIXEL-PAIR form:
    // 512 pair-items = 64 row-pairs x 8 chan-granules; 2 pair-items/thread.
    // Pair (me, me+1): even/odd output px in same output row; shared cols.
    #pragma unroll 1
    for (int pp = 0; pp < 2; ++pp) {
        int j  = tid + pp * 256;
        int rp = j >> 3, q = j & 7;
        int me  = rp * 2;                     // even tile row
        int pos = (int)((m0 + me) & 1023);    // even -> oxe even, same oy pair
        int oy  = pos >> 5, oxe = pos & 31;
        int c0  = q * 8;
        int iy0 = oy * 2 - 1, ix0 = oxe * 2 - 1;

        float sc[8], sh[8];
        #pragma unroll
        for (int ch = 0; ch < 8; ++ch) { sc[ch] = scL[c0 + ch]; sh[ch] = shL[c0 + ch]; }

        float ae[8], ao[8];
        #pragma unroll
        for (int ch = 0; ch < 8; ++ch) { ae[ch] = 0.f; ao[ch] = 0.f; }

        #pragma unroll 1
        for (int kh = 0; kh < 4; ++kh) {
            int iy  = iy0 + kh;
            int iyc = min(max(iy, 0), 63);
            bool oky = ((unsigned)iy < 64u);
            uint4 v[6];
            #pragma unroll
            for (int cc = 0; cc < 6; ++cc) {
                int ix  = ix0 + cc;
                int ixc = min(max(ix, 0), 63);
                v[cc] = *(const uint4*)&y1[((long)(b * 64 + iyc) * 64 + ixc) * 64 + c0];
            }
            #pragma unroll
            for (int kw = 0; kw < 4; ++kw) {
                int t = kh * 4 + kw;
                float4 wa = *(const float4*)&klds[t * 64 + c0];
                float4 wb = *(const float4*)&klds[t * 64 + c0 + 4];
                const float wt[8] = {wa.x, wa.y, wa.z, wa.w, wb.x, wb.y, wb.z, wb.w};
                // even pixel: column kw
                {
                    int ix = ix0 + kw;
                    bool ok = oky && ((unsigned)ix < 64u);
                    #pragma unroll
                    for (int ch = 0; ch < 8; ++ch) {
                        unsigned uu = ((const unsigned*)&v[kw])[ch >> 1];
                        unsigned bits = (ch & 1) ? (uu & 0xffff0000u) : (uu << 16);
                        float xb = ok ? fmaf(__uint_as_float(bits), sc[ch], sh[ch]) : 0.f;
                        ae[ch] = fmaf(xb, wt[ch], ae[ch]);
                    }
                }
                // odd pixel: column kw+2
                {
                    int ix = ix0 + 2 + kw;
                    bool ok = oky && ((unsigned)ix < 64u);
                    #pragma unroll
                    for (int ch = 0; ch < 8; ++ch) {
                        unsigned uu = ((const unsigned*)&v[kw + 2])[ch >> 1];
                        unsigned bits = (ch & 1) ? (uu & 0xffff0000u) : (uu << 16);
                        float xb = ok ? fmaf(__uint_as_float(bits), sc[ch], sh[ch]) : 0.f;
                        ao[ch] = fmaf(xb, wt[ch], ao[ch]);
                    }
                }
            }
        }
        union { uint4 u4; unsigned short us[8]; } pe, po;
        #pragma unroll
        for (int ch = 0; ch < 8; ++ch) { pe.us[ch] = f2b(ae[ch]); po.us[ch] = f2b(ao[ch]); }
        *(uint4*)&As[me * SK + q * 8]       = pe.u4;
        *(uint4*)&As[(me + 1) * SK + q * 8] = po.u4;
    }
    __syncthreads();

    floatx4 acc[4][4];
    #pragma unroll
    for (int i = 0; i < 4; ++i)
        #pragma unroll
        for (int j = 0; j < 4; ++j) acc[i][j] = (floatx4)0.0f;
    #pragma unroll
    for (int h = 0; h < 2; ++h) {
        short8 af[4], bfr[4];
        #pragma unroll
        for (int i = 0; i < 4; ++i) {
            af[i]  = *(const short8*)&As[(wm + i * 16 + lm) * SK + h * 32 + lq * 8];
            bfr[i] = *(const short8*)&Bs[(wn + i * 16 + lm) * SK + h * 32 + lq * 8];
        }
        #pragma unroll
        for (int i = 0; i < 4; ++i)
            #pragma unroll
            for (int j = 0; j < 4; ++j)
                acc[i][j] = __builtin_amdgcn_mfma_f32_16x16x32_bf16(af[i], bfr[j], acc[i][j], 0, 0, 0);
    }
    __syncthreads();

    float bj[4];
    #pragma unroll
    for (int j = 0; j < 4; ++j) bj[j] = bias[wn + j * 16 + lm];

    if (tid < 128) { sums[tid] = 0.f; sqs[tid] = 0.f; }   // klds region, dead
    #pragma unroll
    for (int i = 0; i < 4; ++i)
        #pragma unroll
        for (int j = 0; j < 4; ++j) {
            int c = wn + j * 16 + lm;
            #pragma unroll
            for (int rg = 0; rg < 4; ++rg) {
                int r = wm + i * 16 + lq * 4 + rg;
                float v = acc[i][j][rg] + bj[j];
                v = v > 0.f ? v : 0.2f * v;
                Csh[r * CS + c] = f2b(v);
            }
        }
    __syncthreads();
    {
        const int cg = tid & 15, mr = tid >> 4;
        float sacc[8], qacc[8];
        #pragma unroll
        for (int t = 0; t < 8; ++t) { sacc[t] = 0.f; qacc[t] = 0.f; }
        #pragma unroll
        for (int it = 0; it < 8; ++it) {
            int m = mr + it * 16;
            uint4 pk = *(const uint4*)&Csh[m * CS + cg * 8];
            *(uint4*)&y[(m0 + m) * 128 + cg * 8] = pk;
            const unsigned short* pu = (const unsigned short*)&pk;
            #pragma unroll
            for (int t = 0; t < 8; ++t) {
                float f = b2f(pu[t]);
                sacc[t] += f;
                qacc[t] = fmaf(f, f, qacc[t]);
            }
        }
        #pragma unroll
        for (int t = 0; t < 8; ++t) {
            atomicAdd(&sums[cg * 8 + t], sacc[t]);
            atomicAdd(&sqs [cg * 8 + t], qacc[t]);
        }
    }
    __syncthreads();
    {
        const int rep = blockIdx.x & (NREP - 1);
        if (tid < 128) {
            atomicAdd(&statsOut[rep * 256 + tid],        sums[tid]);
            atomicAdd(&statsOut[rep * 256 + 128 + tid],  sqs[tid]);
        }
    }
}

// ---------------------------------------------------------------------------
// Direct-tap depthwise conv (layers 3..5): thread = (output pixel, 8 ch).
// BN affine computed in-kernel from the previous layer's stats replicas.
// ---------------------------------------------------------------------------
template<int C, int KS, int HIN, int HOUT, int STRIDE, int PAD, int NTHR>
__global__ __launch_bounds__(NTHR) void dw_direct(
    const bf16* __restrict__ x, const float* __restrict__ st,
    const float* __restrict__ gam, const float* __restrict__ bet,
    float NINV, const float* __restrict__ dynkT, bf16* __restrict__ outA)
{
    constexpr int G   = C / 8;
    constexpr int KSK = KS * KS;
    static_assert(NTHR == HOUT * G, "one output row per block");

    __shared__ __align__(16) float wlds[KSK * C];
    __shared__ float affs[2 * C];

    const int tid = threadIdx.x;
    const int b   = blockIdx.x / HOUT;
    const int oy  = blockIdx.x % HOUT;

    {
        const float* src = dynkT + (long)b * (KSK * C);
        for (int i = tid * 4; i < KSK * C; i += NTHR * 4)
            *(float4*)&wlds[i] = *(const float4*)&src[i];
    }
    for (int c = tid; c < C; c += NTHR) {     // folded bn_prep
        float s = 0.f, q = 0.f;
        #pragma unroll
        for (int r = 0; r < NREP; ++r) {
            s += st[r * 2 * C + c];
            q += st[r * 2 * C + C + c];
        }
        float m   = s * NINV;
        float var = fmaf(q, NINV, -m * m);
        float sc  = gam[c] * rsqrtf(var + 1e-5f);
        affs[c]     = sc;
        affs[C + c] = fmaf(-m, sc, bet[c]);
    }
    __syncthreads();

    const int g  = tid % G;
    const int ox = tid / G;
    const int c0 = g * 8;
    const int iy0 = oy * STRIDE - PAD;
    const int ix0 = ox * STRIDE - PAD;

    float sc[8], sh[8];
    #pragma unroll
    for (int ch = 0; ch < 8; ++ch) {
        sc[ch] = affs[c0 + ch];
        sh[ch] = affs[C + c0 + ch];
    }

    float acc[8];
    #pragma unroll
    for (int ch = 0; ch < 8; ++ch) acc[ch] = 0.f;

    const bool interior = (iy0 >= 0) && (iy0 + KS <= HIN) &&
                          (ix0 >= 0) && (ix0 + KS <= HIN);

    if (interior) {
        const bf16* bp = x + ((long)(b * HIN + iy0) * HIN + ix0) * C + c0;
        uint4 v[KSK];
        #pragma unroll
        for (int kh = 0; kh < KS; ++kh)
            #pragma unroll
            for (int kw = 0; kw < KS; ++kw)
                v[kh * KS + kw] = *(const uint4*)(bp + (kh * HIN + kw) * C);
        #pragma unroll
        for (int t = 0; t < KSK; ++t) {
            const float* wp = &wlds[t * C + c0];
            float4 wa = *(const float4*)wp;
            float4 wb = *(const float4*)(wp + 4);
            const float wt[8] = {wa.x, wa.y, wa.z, wa.w, wb.x, wb.y, wb.z, wb.w};
            #pragma unroll
            for (int ch = 0; ch < 8; ++ch) {
                unsigned u = ((const unsigned*)&v[t])[ch >> 1];
                unsigned bits = (ch & 1) ? (u & 0xffff0000u) : (u << 16);
                float xb = fmaf(__uint_as_float(bits), sc[ch], sh[ch]);
                acc[ch] = fmaf(xb, wt[ch], acc[ch]);
            }
        }
    } else {
        #pragma unroll
        for (int kh = 0; kh < KS; ++kh) {
            const int iy = iy0 + kh;
            if ((unsigned)iy >= (unsigned)HIN) continue;
            #pragma unroll
            for (int kw = 0; kw < KS; ++kw) {
                const int ix = ix0 + kw;
                if ((unsigned)ix >= (unsigned)HIN) continue;
                uint4 v = *(const uint4*)&x[((long)(b * HIN + iy) * HIN + ix) * C + c0];
                const float* wp = &wlds[(kh * KS + kw) * C + c0];
                float4 wa = *(const float4*)wp;
                float4 wb = *(const float4*)(wp + 4);
                const float wt[8] = {wa.x, wa.y, wa.z, wa.w, wb.x, wb.y, wb.z, wb.w};
                #pragma unroll
                for (int ch = 0; ch < 8; ++ch) {
                    unsigned u = ((const unsigned*)&v)[ch >> 1];
                    unsigned bits = (ch & 1) ? (u & 0xffff0000u) : (u << 16);
                    float xb = fmaf(__uint_as_float(bits), sc[ch], sh[ch]);
                    acc[ch] = fmaf(xb, wt[ch], acc[ch]);
                }
            }
        }
    }

    union { uint4 v; unsigned short us[8]; } pk;
    #pragma unroll
    for (int ch = 0; ch < 8; ++ch) pk.us[ch] = f2b(acc[ch]);
    *(uint4*)&outA[((long)(b * HOUT + oy) * HOUT + ox) * C + c0] = pk.v;
}

// ---------------------------------------------------------------------------
// MFMA bf16 GEMM: C[M,COUT] = A[M,K] x W[K,COUT], 128x128 block tile, BK=64.
// ---------------------------------------------------------------------------
template<int K, int COUT, bool LAST>
__global__ __launch_bounds__(256) void gemm_layer(
    const bf16* __restrict__ A, const bf16* __restrict__ WT,
    const float* __restrict__ bias, bf16* __restrict__ y,
    float* __restrict__ statsOut, float* __restrict__ outF, int Mtiles)
{
    constexpr int SK = 72;
    constexpr int CS = 136;
    __shared__ __align__(16) unsigned short smem[18432];
    unsigned short* As  = smem;
    unsigned short* Bs  = smem + 9216;
    unsigned short* Csh = smem;
    __shared__ float sums[128], sqs[128];

    const int tid  = threadIdx.x;
    const int lane = tid & 63;
    const int w    = tid >> 6;
    const int wm   = (w >> 1) * 64, wn = (w & 1) * 64;
    const int lm   = lane & 15, lq = lane >> 4;
    const int mt   = blockIdx.x % Mtiles;
    const int nt   = blockIdx.x / Mtiles;
    const long m0  = (long)mt * 128;
    const int  n0  = nt * 128;

    floatx4 acc[4][4];
    #pragma unroll
    for (int i = 0; i < 4; ++i)
        #pragma unroll
        for (int j = 0; j < 4; ++j) acc[i][j] = (floatx4)0.0f;

    for (int kb = 0; kb < K; kb += 64) {
        __syncthreads();
        #pragma unroll
        for (int s = 0; s < 4; ++s) {
            int i = tid + s * 256;
            int m = i >> 3, q = i & 7;
            uint4 va = *(const uint4*)(A  + ((m0 + m) * K + kb + q * 8));
            uint4 vb = *(const uint4*)(WT + ((long)(n0 + m) * K + kb + q * 8));
            *(uint4*)&As[m * SK + q * 8] = va;
            *(uint4*)&Bs[m * SK + q * 8] = vb;
        }
        __syncthreads();
        #pragma unroll
        for (int h = 0; h < 2; ++h) {
            short8 af[4], bfr[4];
            #pragma unroll
            for (int i = 0; i < 4; ++i) {
                af[i]  = *(const short8*)&As[(wm + i * 16 + lm) * SK + h * 32 + lq * 8];
                bfr[i] = *(const short8*)&Bs[(wn + i * 16 + lm) * SK + h * 32 + lq * 8];
            }
            #pragma unroll
            for (int i = 0; i < 4; ++i)
                #pragma unroll
                for (int j = 0; j < 4; ++j)
                    acc[i][j] = __builtin_amdgcn_mfma_f32_16x16x32_bf16(af[i], bfr[j], acc[i][j], 0, 0, 0);
        }
    }
    __syncthreads();

    float bj[4];
    #pragma unroll
    for (int j = 0; j < 4; ++j) bj[j] = bias[n0 + wn + j * 16 + lm];

    if constexpr (!LAST) {
        if (tid < 128) { sums[tid] = 0.f; sqs[tid] = 0.f; }
        #pragma unroll
        for (int i = 0; i < 4; ++i)
            #pragma unroll
            for (int j = 0; j < 4; ++j) {
                int c = wn + j * 16 + lm;
                #pragma unroll
                for (int rg = 0; rg < 4; ++rg) {
                    int r = wm + i * 16 + lq * 4 + rg;
                    float v = acc[i][j][rg] + bj[j];
                    v = v > 0.f ? v : 0.2f * v;
                    Csh[r * CS + c] = f2b(v);
                }
            }
        __syncthreads();
        const int cg = tid & 15, mr = tid >> 4;
        float sacc[8], qacc[8];
        #pragma unroll
        for (int t = 0; t < 8; ++t) { sacc[t] = 0.f; qacc[t] = 0.f; }
        #pragma unroll
        for (int it = 0; it < 8; ++it) {
            int m = mr + it * 16;
            uint4 pk = *(const uint4*)&Csh[m * CS + cg * 8];
            *(uint4*)&y[(m0 + m) * COUT + n0 + cg * 8] = pk;
            const unsigned short* pu = (const unsigned short*)&pk;
            #pragma unroll
            for (int t = 0; t < 8; ++t) {
                float f = b2f(pu[t]);
                sacc[t] += f;
                qacc[t] = fmaf(f, f, qacc[t]);
            }
        }
        #pragma unroll
        for (int t = 0; t < 8; ++t) {
            atomicAdd(&sums[cg * 8 + t], sacc[t]);
            atomicAdd(&sqs [cg * 8 + t], qacc[t]);
        }
        __syncthreads();
        {
            const int rep = blockIdx.x & (NREP - 1);
            if (tid < 128) {
                atomicAdd(&statsOut[rep * 2 * COUT + n0 + tid],        sums[tid]);
                atomicAdd(&statsOut[rep * 2 * COUT + COUT + n0 + tid], sqs[tid]);
            }
        }
    } else {
        #pragma unroll
        for (int i = 0; i < 4; ++i)
            #pragma unroll
            for (int j = 0; j < 4; ++j) {
                int c  = wn + j * 16 + lm;
                int rb = wm + i * 16 + lq * 4;
                ushort4 pk;
                unsigned short* pp = (unsigned short*)&pk;
                #pragma unroll
                for (int rg = 0; rg < 4; ++rg)
                    pp[rg] = f2b(acc[i][j][rg] + bj[j]);
                *(ushort4*)&Csh[c * CS + rb] = pk;
            }
        __syncthreads();
        const int mg = tid & 15, nr = tid >> 4;
        #pragma unroll
        for (int it = 0; it < 8; ++it) {
            int n = nr + it * 16;
            uint4 pk = *(const uint4*)&Csh[n * CS + mg * 8];
            const unsigned short* pu = (const unsigned short*)&pk;
            #pragma unroll
            for (int t = 0; t < 8; ++t) {
                int m = (int)m0 + mg * 8 + t;
                int b = m / 49, pos = m - b * 49;
                float v = b2f(pu[t]);
                outF[((long)(b * 512 + n0 + n)) * 49 + pos] = 1.f / (1.f + __expf(-v));
            }
        }
    }
}

// ---------------------------------------------------------------------------

extern "C" void kernel_launch(void* const* d_in, const int* in_sizes, int n_in,
                              void* d_out, int out_size, void* d_ws, size_t ws_size,
                              hipStream_t stream)
{
    const float* input = (const float*)d_in[0];
    const int*   label = (const int*)d_in[1];
    const float* emb   = (const float*)d_in[2];
    const float* lw[5] = {(const float*)d_in[3], (const float*)d_in[5], (const float*)d_in[7],
                          (const float*)d_in[9], (const float*)d_in[11]};
    const float* lb[5] = {(const float*)d_in[4], (const float*)d_in[6], (const float*)d_in[8],
                          (const float*)d_in[10], (const float*)d_in[12]};
    const float* cmw[5] = {(const float*)d_in[13], (const float*)d_in[15], (const float*)d_in[17],
                           (const float*)d_in[19], (const float*)d_in[21]};
    const float* cmb[5] = {(const float*)d_in[14], (const float*)d_in[16], (const float*)d_in[18],
                           (const float*)d_in[20], (const float*)d_in[22]};
    const float* bng[4] = {(const float*)d_in[23], (const float*)d_in[25],
                           (const float*)d_in[27], (const float*)d_in[29]};
    const float* bnb[4] = {(const float*)d_in[24], (const float*)d_in[26],
                           (const float*)d_in[28], (const float*)d_in[30]};
    float* out = (float*)d_out;

    float* wsf   = (float*)d_ws;
    float* dynk  = wsf;
    float* stats = wsf + 1071104;
    const float* k1  = dynk;
    const float* k2T = dynk + 6144;
    const float* k3T = dynk + 137216;
    const float* k4T = dynk + 284672;
    const float* k5T = dynk + 808960;
    float* st1 = stats;
    float* st2 = stats + 2048;
    float* st3 = stats + 6144;
    float* st4 = stats + 14336;

    bf16* wt  = (bf16*)((char*)d_ws + 4407296);
    bf16* wt2 = wt;
    bf16* wt3 = wt + 8192;
    bf16* wt4 = wt + 40960;
    bf16* wt5 = wt + 172032;
    bf16* S1  = (bf16*)((char*)d_ws + 5308416);    // 33554432 elems capacity
    bf16* S2  = (bf16*)((char*)d_ws + 72417280);   // y2: 16777216 elems (33.5 MB)

    // S1 sub-regions for the L3..L5 chain (elems; y1 dead after gemm2_fused).
    // Sizes: A3 4194304 | y3 8388608 | A4 2097152 | y4 4194304 | A5 3211264.
    bf16* A3 = S1;                   // ends  4194304
    bf16* y3 = S1 + 4194304;         // ends 12582912
    bf16* A4 = S1 + 12582912;        // ends 14680064
    bf16* y4 = S1 + 14680064;        // ends 18874368
    bf16* A5 = S1 + 18874368;        // ends 22085632 < 33554432

    // Merged head: prep (4186 blocks) + wt (424 blocks) in one dispatch.
    prep_wt_kernel<<<4610, 256, 0, stream>>>(label, emb,
        lw[0], lb[0], lw[1], lb[1], lw[2], lb[2], lw[3], lb[3], lw[4], lb[4],
        dynk, stats, out + 3211264,
        cmw[1], cmw[2], cmw[3], cmw[4], wt2, wt3, wt4, wt5);

    // L1: fused (K=3) -> y1 @ S1 + st1
    fused_l1_v6<<<2048, 256, 0, stream>>>(input, k1, cmw[0], cmb[0], S1, st1);

    // L2: dw fused into gemm A-staging (pixel-pair, 4/CU); bn1 in-kernel.
    gemm2_fused<<<1024, 256, 0, stream>>>(S1, wt2, st1, bng[0], bnb[0],
                                          k2T, cmb[1], S2, st2);

    // L3: y2 (S2) -> A3 (S1) -> y3; bn2 affine in-kernel.
    dw_direct<128, 3, 32, 16, 2, 1, 256><<<2048, 256, 0, stream>>>(
        S2, st2, bng[1], bnb[1], 1.f / 131072.f, k3T, A3);
    gemm_layer<128, 256, false><<<512, 256, 0, stream>>>(
        A3, wt3, cmb[2], y3, st3, nullptr, 256);

    // L4: y3 -> A4 -> y4; bn3 affine in-kernel.
    dw_direct<256, 4, 16, 8, 2, 1, 256><<<1024, 256, 0, stream>>>(
        y3, st3, bng[2], bnb[2], 1.f / 32768.f, k4T, A4);
    gemm_layer<256, 512, false><<<256, 256, 0, stream>>>(
        A4, wt4, cmb[3], y4, st4, nullptr, 64);

    // L5: y4 -> A5 -> out; bn4 affine in-kernel.
    dw_direct<512, 2, 8, 7, 1, 0, 448><<<896, 448, 0, stream>>>(
        y4, st4, bng[3], bnb[3], 1.f / 8192.f, k5T, A5);
    gemm_layer<512, 512, true><<<196, 256, 0, stream>>>(
        A5, wt5, cmb[4], nullptr, nullptr, out, 49);
}